// Round 5
// baseline (597.819 us; speedup 1.0000x reference)
//
#include <hip/hip_runtime.h>
#include <cstdint>
#include <cstddef>

typedef _Float16 half8 __attribute__((ext_vector_type(8)));
typedef _Float16 half4 __attribute__((ext_vector_type(4)));
typedef float f32x4 __attribute__((ext_vector_type(4)));

#define GAT_N 8192
#define GAT_F 256
#define GAT_NW 256   // adj bitmask words per row (8192/32)
#define GAT_ALPHA 0.2f
#define GAT_LOG2E 1.4426950408889634f

// Monotone float->uint encoding for atomicMax over floats of any sign.
__device__ inline unsigned enc_f32(float x) {
    unsigned b = __float_as_uint(x);
    return (b & 0x80000000u) ? ~b : (b | 0x80000000u);
}
__device__ inline float dec_f32(unsigned u) {
    unsigned b = (u & 0x80000000u) ? (u ^ 0x80000000u) : ~u;
    return __uint_as_float(b);
}

// ---------------------------------------------------------------------------
// K0a: bit-pack adj (int32 0/1, 268 MB) -> adjB (1 bit/edge, 8 MB).
// One wave per row; byte b of a row covers keys [8b, 8b+8), bit j = key 8b+j.
// ---------------------------------------------------------------------------
__global__ __launch_bounds__(256) void gat_k0_pack(
    const int* __restrict__ adj, unsigned char* __restrict__ adjB)
{
    const int wv = threadIdx.x >> 6;
    const int lane = threadIdx.x & 63;
    const int row = blockIdx.x * 4 + wv;
    const int* src = adj + (size_t)row * GAT_N;
    unsigned char* dst = adjB + (size_t)row * (GAT_N / 8);
    #pragma unroll 4
    for (int k = 0; k < 16; ++k) {
        const int4 v0 = *reinterpret_cast<const int4*>(src + k * 512 + lane * 8);
        const int4 v1 = *reinterpret_cast<const int4*>(src + k * 512 + lane * 8 + 4);
        unsigned m = (unsigned)(v0.x > 0)        | ((unsigned)(v0.y > 0) << 1)
                   | ((unsigned)(v0.z > 0) << 2) | ((unsigned)(v0.w > 0) << 3)
                   | ((unsigned)(v1.x > 0) << 4) | ((unsigned)(v1.y > 0) << 5)
                   | ((unsigned)(v1.z > 0) << 6) | ((unsigned)(v1.w > 0) << 7);
        dst[k * 64 + lane] = (unsigned char)m;
    }
}

// ---------------------------------------------------------------------------
// K0b: W -> fp16 transposed WT[n][k]; init encoded f2max.
// ---------------------------------------------------------------------------
__global__ __launch_bounds__(256) void gat_k0b_convert(
    const float* __restrict__ W, _Float16* __restrict__ WT,
    unsigned* __restrict__ f2mxEnc)
{
    const int g = blockIdx.x * 256 + threadIdx.x;      // 65536 threads
    if (g == 0) *f2mxEnc = 0u;                          // enc(-FLT_MAX)
    const int k = g >> 8, n = g & 255;
    WT[n * GAT_F + k] = (_Float16)W[g];
}

// ---------------------------------------------------------------------------
// K1: Wh = h @ W via fp16 MFMA. grid 512 x 256 thr: block = 16 rows,
// wave wv = col-quarter (64 cols, 4 tiles, acc 16 VGPR). Fully unrolled
// k-loop (16 A + 16 B loads in flight). Cross-wave f1/f2 combine via LDS;
// one atomicMax per block. 2 blocks/CU, 2 waves/SIMD.
// ---------------------------------------------------------------------------
__global__ __launch_bounds__(256, 2) void gat_k1_gemm(
    const float* __restrict__ h, const _Float16* __restrict__ WT,
    const float* __restrict__ a, _Float16* __restrict__ whT,
    float* __restrict__ f1L, float* __restrict__ f2L,
    unsigned* __restrict__ f2mxEnc)
{
    __shared__ float sP1[4][16], sP2[4][16];
    const int wv = threadIdx.x >> 6;       // col-quarter
    const int lane = threadIdx.x & 63;
    const int l15 = lane & 15;
    const int quad = lane >> 4;
    const int r0 = blockIdx.x * 16;

    f32x4 acc[4];
    #pragma unroll
    for (int t = 0; t < 4; ++t) { f32x4 z = {0.f,0.f,0.f,0.f}; acc[t] = z; }

    #pragma unroll
    for (int k0 = 0; k0 < GAT_F; k0 += 32) {
        const float* ap = h + (size_t)(r0 + l15) * GAT_F + k0 + quad * 8;
        const float4 a0 = *reinterpret_cast<const float4*>(ap);
        const float4 a1 = *reinterpret_cast<const float4*>(ap + 4);
        half8 af;
        af[0] = (_Float16)a0.x; af[1] = (_Float16)a0.y;
        af[2] = (_Float16)a0.z; af[3] = (_Float16)a0.w;
        af[4] = (_Float16)a1.x; af[5] = (_Float16)a1.y;
        af[6] = (_Float16)a1.z; af[7] = (_Float16)a1.w;
        #pragma unroll
        for (int t = 0; t < 4; ++t) {
            half8 bf = *reinterpret_cast<const half8*>(
                WT + (size_t)(wv * 64 + t * 16 + l15) * GAT_F + k0 + quad * 8);
            acc[t] = __builtin_amdgcn_mfma_f32_16x16x32_f16(af, bf, acc[t], 0, 0, 0);
        }
    }

    // Partial f1/f2 over this wave's 64 cols.
    float p1[4] = {0.f,0.f,0.f,0.f}, p2[4] = {0.f,0.f,0.f,0.f};
    #pragma unroll
    for (int t = 0; t < 4; ++t) {
        float a1c = a[wv * 64 + t * 16 + l15];
        float a2c = a[GAT_F + wv * 64 + t * 16 + l15];
        #pragma unroll
        for (int r = 0; r < 4; ++r) {
            p1[r] = fmaf(acc[t][r], a1c, p1[r]);
            p2[r] = fmaf(acc[t][r], a2c, p2[r]);
        }
    }
    #pragma unroll
    for (int off = 1; off < 16; off <<= 1) {
        #pragma unroll
        for (int r = 0; r < 4; ++r) {
            p1[r] += __shfl_xor(p1[r], off);
            p2[r] += __shfl_xor(p2[r], off);
        }
    }
    if (l15 == 0) {
        #pragma unroll
        for (int r = 0; r < 4; ++r) {
            sP1[wv][quad * 4 + r] = p1[r];
            sP2[wv][quad * 4 + r] = p2[r];
        }
    }
    __syncthreads();
    if (threadIdx.x < 16) {
        const int row = threadIdx.x;
        const float s1 = (sP1[0][row] + sP1[1][row] + sP1[2][row] + sP1[3][row]) * GAT_LOG2E;
        const float s2 = (sP2[0][row] + sP2[1][row] + sP2[2][row] + sP2[3][row]) * GAT_LOG2E;
        f1L[r0 + row] = s1;
        f2L[r0 + row] = s2;
        float mx = s2;
        #pragma unroll
        for (int off = 1; off < 16; off <<= 1) mx = fmaxf(mx, __shfl_xor(mx, off));
        if (row == 0) atomicMax(f2mxEnc, enc_f32(mx));
    }

    // whT[col][row] fp16 store.
    #pragma unroll
    for (int t = 0; t < 4; ++t) {
        half4 hv;
        #pragma unroll
        for (int r = 0; r < 4; ++r) hv[r] = (_Float16)acc[t][r];
        *reinterpret_cast<half4*>(
            whT + (size_t)(wv * 64 + t * 16 + l15) * GAT_N + r0 + quad * 4) = hv;
    }
}

// ---------------------------------------------------------------------------
// K3: fused masked softmax-numerator x V via fp16 MFMA, bitmask adjacency,
// LDS-staged B-tiles, feature-split for occupancy.
// grid = 64 rb x 8 q x 2 fh = 1024 blocks, 4 blocks/CU (16 waves/CU).
// Block: 128 rows x 128 feats x 1024-key slice; wave: 32 rows (2 strips),
// acc = 2x8x4 = 64 VGPR. Per step stage 128-feat x 32-key tile (8 KB) via
// global_load_lds double-buffer; B-frags via ds_read_b128.
// ---------------------------------------------------------------------------
__global__ __launch_bounds__(256, 4) void gat_k3_attn(
    const unsigned* __restrict__ adjW, const float* __restrict__ f1L,
    const float* __restrict__ f2L, const unsigned* __restrict__ f2mxEnc,
    const _Float16* __restrict__ whT,
    _Float16* __restrict__ Ph,     // 8 slabs x 8192x256 fp16, permuted
    float* __restrict__ L)         // [8][8192]
{
    __shared__ __align__(16) _Float16 sB[2][128 * 32];  // [buf][fl*32+key]

    const int bx = blockIdx.x;
    const int q  = bx & 7;           // key slice (bx%8 ~ XCD spread)
    const int fh = (bx >> 3) & 1;    // feature half
    const int rb = bx >> 4;          // row group 0..63
    const int wv = threadIdx.x >> 6;
    const int lane = threadIdx.x & 63;
    const int l15 = lane & 15;
    const int quad = lane >> 4;

    const int r0 = rb * 128 + wv * 32;
    const int rA = r0 + l15;
    const int rB = rA + 16;

    const float fmxL = dec_f32(*f2mxEnc);
    const float f1A = f1L[rA];
    const float f1B = f1L[rB];
    const float sA = f1A + fmxL;
    const float sBv = f1B + fmxL;
    const float CA = fmaxf(sA, GAT_ALPHA * sA);
    const float CB = fmaxf(sBv, GAT_ALPHA * sBv);

    f32x4 acc[2][8];
    #pragma unroll
    for (int s = 0; s < 2; ++s)
        #pragma unroll
        for (int t = 0; t < 8; ++t) {
            f32x4 z = {0.f,0.f,0.f,0.f};
            acc[s][t] = z;
        }
    float d0 = 0.f, d1 = 0.f;

    const int kq = q * 1024;
    const uint4* awA = reinterpret_cast<const uint4*>(adjW + (size_t)rA * GAT_NW + q * 32);
    const uint4* awB = reinterpret_cast<const uint4*>(adjW + (size_t)rB * GAT_NW + q * 32);
    const float* f2q = f2L + kq + quad * 8;

    // Staging: wave wv covers local feats [wv*32, wv*32+32).
    // Lane pattern: feat += lane>>2, key oct = lane&3 -> lds off = lane*16 B.
    const _Float16* gstage = whT
        + (size_t)(fh * 128 + wv * 32 + (lane >> 2)) * GAT_N + kq + (lane & 3) * 8;

    #define STAGE(buf, step)                                                   \
        {                                                                      \
            _Float16* lp = &sB[buf][wv * 1024];                                \
            const _Float16* gp = gstage + (step) * 32;                         \
            __builtin_amdgcn_global_load_lds(                                  \
                (const __attribute__((address_space(1))) void*)gp,             \
                (__attribute__((address_space(3))) void*)lp, 16, 0, 0);        \
            __builtin_amdgcn_global_load_lds(                                  \
                (const __attribute__((address_space(1))) void*)                \
                    (gp + (size_t)16 * GAT_N),                                 \
                (__attribute__((address_space(3))) void*)(lp + 512),           \
                16, 0, 0);                                                     \
        }

    STAGE(0, 0)
    uint4 nA = awA[0];
    uint4 nB = awB[0];
    float4 nfa = *reinterpret_cast<const float4*>(f2q);
    float4 nfb = *reinterpret_cast<const float4*>(f2q + 4);
    __syncthreads();   // buf0 staged (barrier semantics drain vmcnt)

    for (int g = 0; g < 8; ++g) {
        const uint4 cA = nA, cB = nB;
        if (g < 7) { nA = awA[g + 1]; nB = awB[g + 1]; }

        #pragma unroll
        for (int s4 = 0; s4 < 4; ++s4) {
            const int step = g * 4 + s4;
            const int cur = step & 1;
            if (step + 1 < 32) STAGE(1 - cur, step + 1)

            const float4 cfa = nfa, cfb = nfb;
            if (step < 31) {
                nfa = *reinterpret_cast<const float4*>(f2q + (step + 1) * 32);
                nfb = *reinterpret_cast<const float4*>(f2q + (step + 1) * 32 + 4);
            }
            const unsigned wA = (s4 == 0) ? cA.x : (s4 == 1) ? cA.y : (s4 == 2) ? cA.z : cA.w;
            const unsigned wB = (s4 == 0) ? cB.x : (s4 == 1) ? cB.y : (s4 == 2) ? cB.z : cB.w;
            const unsigned mA = (wA >> (quad * 8)) & 0xffu;
            const unsigned mB = (wB >> (quad * 8)) & 0xffu;
            const float f2v[8] = {cfa.x, cfa.y, cfa.z, cfa.w, cfb.x, cfb.y, cfb.z, cfb.w};

            half8 pA, pB;
            #pragma unroll
            for (int j = 0; j < 8; ++j) {
                const float f2j = f2v[j];
                float xa = f1A + f2j;
                float la = fmaxf(xa, GAT_ALPHA * xa);
                float pa = __builtin_amdgcn_exp2f(la - CA);
                pa = (mA & (1u << j)) ? pa : 0.f;
                d0 += pa;
                pA[j] = (_Float16)pa;
                float xb = f1B + f2j;
                float lb = fmaxf(xb, GAT_ALPHA * xb);
                float pb = __builtin_amdgcn_exp2f(lb - CB);
                pb = (mB & (1u << j)) ? pb : 0.f;
                d1 += pb;
                pB[j] = (_Float16)pb;
            }

            #pragma unroll
            for (int t = 0; t < 8; ++t) {
                half8 bf = *reinterpret_cast<const half8*>(
                    &sB[cur][(t * 16 + l15) * 32 + quad * 8]);
                acc[0][t] = __builtin_amdgcn_mfma_f32_16x16x32_f16(pA, bf, acc[0][t], 0, 0, 0);
                acc[1][t] = __builtin_amdgcn_mfma_f32_16x16x32_f16(pB, bf, acc[1][t], 0, 0, 0);
            }
            __syncthreads();   // drains stage(step+1) + this step's ds_reads
        }
    }
    #undef STAGE

    // Row denominators (identical in both fh blocks; fh==0 writes).
    d0 += __shfl_xor(d0, 16); d0 += __shfl_xor(d0, 32);
    d1 += __shfl_xor(d1, 16); d1 += __shfl_xor(d1, 32);
    if (fh == 0 && lane < 16) {
        float* Lq = L + q * GAT_N;
        Lq[rA] = d0; Lq[rB] = d1;
    }

    // Coalesced permuted fp16 partial store; fh selects tile range.
    const int wid = rb * 4 + wv;                       // 0..255
    _Float16* Pq = Ph + ((size_t)q * 256 + wid) * 8192;
    #pragma unroll
    for (int s = 0; s < 2; ++s)
        #pragma unroll
        for (int t = 0; t < 8; ++t) {
            const int tt = fh * 8 + t;
            half4 hv;
            #pragma unroll
            for (int r = 0; r < 4; ++r) hv[r] = (_Float16)acc[s][t][r];
            *reinterpret_cast<half4*>(Pq + (size_t)(((s * 16 + tt) * 64 + lane) * 4)) = hv;
        }
}

// ---------------------------------------------------------------------------
// K4: un-permute + combine 8 fp16 partials, normalize, ELU, write out.
// ---------------------------------------------------------------------------
__global__ __launch_bounds__(256) void gat_k4_final(
    const _Float16* __restrict__ Ph, const float* __restrict__ L,
    float* __restrict__ out)
{
    const int tid = threadIdx.x;
    const int wid = blockIdx.x >> 3;                   // wave-chunk 0..255
    __shared__ float s_rl[32];
    if (tid < 32) {
        const int row = wid * 32 + tid;
        float s = 0.f;
        #pragma unroll
        for (int q = 0; q < 8; ++q) s += L[q * GAT_N + row];
        s_rl[tid] = 1.0f / fmaxf(s, 1e-30f);
    }
    __syncthreads();

    const int idx = blockIdx.x * 256 + tid;            // half4 position
    const int rem = idx & 2047;                        // within wave-chunk
    const int lane = rem & 63;
    const int st = rem >> 6;
    const int s = st >> 4, t = st & 15;
    const int l15 = lane & 15, quad = lane >> 4;
    const int lrow0 = s * 16 + quad * 4;               // local rows lrow0..+3
    const int col = t * 16 + l15;

    float accv[4] = {0.f, 0.f, 0.f, 0.f};
    #pragma unroll
    for (int q = 0; q < 8; ++q) {
        half4 v = *reinterpret_cast<const half4*>(
            Ph + ((size_t)q * 256 + wid) * 8192 + (size_t)rem * 4);
        #pragma unroll
        for (int r = 0; r < 4; ++r) accv[r] += (float)v[r];
    }
    #pragma unroll
    for (int r = 0; r < 4; ++r) {
        const float v = accv[r] * s_rl[lrow0 + r];
        const float o = v > 0.f ? v : expm1f(v);
        out[(size_t)(wid * 32 + lrow0 + r) * GAT_F + col] = o;
    }
}

// ---------------------------------------------------------------------------
extern "C" void kernel_launch(void* const* d_in, const int* in_sizes, int n_in,
                              void* d_out, int out_size, void* d_ws, size_t ws_size,
                              hipStream_t stream)
{
    const float* h   = (const float*)d_in[0];
    const int*   adj = (const int*)d_in[1];
    // d_in[2] = cv_values: constant per softmax row -> cancels exactly; unused.
    const float* W   = (const float*)d_in[3];
    const float* a   = (const float*)d_in[4];
    float* out = (float*)d_out;
    char* ws = (char*)d_ws;

    const size_t SLAB = (size_t)GAT_N * GAT_F * 2;     // 4 MiB (fp16 matrix)

    size_t off = 0;
    _Float16* whT = (_Float16*)(ws + off); off += SLAB;            // 4 MiB
    _Float16* Ph  = (_Float16*)(ws + off); off += 8 * SLAB;        // 32 MiB
    unsigned char* adjB = (unsigned char*)(ws + off); off += (size_t)GAT_N * GAT_N / 8; // 8 MiB
    _Float16* WT  = (_Float16*)(ws + off); off += (size_t)GAT_F * GAT_F * 2;            // 128 KiB
    float* f1L = (float*)(ws + off); off += GAT_N * 4;
    float* f2L = (float*)(ws + off); off += GAT_N * 4;
    float* L   = (float*)(ws + off); off += 8 * GAT_N * 4;
    unsigned* f2mxEnc = (unsigned*)(ws + off); off += 256;

    gat_k0_pack<<<2048, 256, 0, stream>>>(adj, adjB);
    gat_k0b_convert<<<256, 256, 0, stream>>>(W, WT, f2mxEnc);
    gat_k1_gemm<<<512, 256, 0, stream>>>(h, WT, a, whT, f1L, f2L, f2mxEnc);
    gat_k3_attn<<<1024, 256, 0, stream>>>((const unsigned*)adjB, f1L, f2L, f2mxEnc, whT, Ph, L);
    gat_k4_final<<<2048, 256, 0, stream>>>(Ph, L, out);
}

// Round 6
// 483.476 us; speedup vs baseline: 1.2365x; 1.2365x over previous
//
#include <hip/hip_runtime.h>
#include <cstdint>
#include <cstddef>

typedef _Float16 half8 __attribute__((ext_vector_type(8)));
typedef _Float16 half4 __attribute__((ext_vector_type(4)));
typedef float f32x4 __attribute__((ext_vector_type(4)));

#define GAT_N 8192
#define GAT_F 256
#define GAT_NW 256   // adj bitmask words per row (8192/32)
#define GAT_ALPHA 0.2f
#define GAT_LOG2E 1.4426950408889634f

// Monotone float->uint encoding for atomicMax over floats of any sign.
__device__ inline unsigned enc_f32(float x) {
    unsigned b = __float_as_uint(x);
    return (b & 0x80000000u) ? ~b : (b | 0x80000000u);
}
__device__ inline float dec_f32(unsigned u) {
    unsigned b = (u & 0x80000000u) ? (u ^ 0x80000000u) : ~u;
    return __uint_as_float(b);
}

// ---------------------------------------------------------------------------
// K0a: bit-pack adj (int32 0/1, 268 MB) -> adjB (1 bit/edge, 8 MB).
// One wave per row; byte b of a row covers keys [8b, 8b+8), bit j = key 8b+j.
// ---------------------------------------------------------------------------
__global__ __launch_bounds__(256) void gat_k0_pack(
    const int* __restrict__ adj, unsigned char* __restrict__ adjB)
{
    const int wv = threadIdx.x >> 6;
    const int lane = threadIdx.x & 63;
    const int row = blockIdx.x * 4 + wv;
    const int* src = adj + (size_t)row * GAT_N;
    unsigned char* dst = adjB + (size_t)row * (GAT_N / 8);
    #pragma unroll 4
    for (int k = 0; k < 16; ++k) {
        const int4 v0 = *reinterpret_cast<const int4*>(src + k * 512 + lane * 8);
        const int4 v1 = *reinterpret_cast<const int4*>(src + k * 512 + lane * 8 + 4);
        unsigned m = (unsigned)(v0.x > 0)        | ((unsigned)(v0.y > 0) << 1)
                   | ((unsigned)(v0.z > 0) << 2) | ((unsigned)(v0.w > 0) << 3)
                   | ((unsigned)(v1.x > 0) << 4) | ((unsigned)(v1.y > 0) << 5)
                   | ((unsigned)(v1.z > 0) << 6) | ((unsigned)(v1.w > 0) << 7);
        dst[k * 64 + lane] = (unsigned char)m;
    }
}

// ---------------------------------------------------------------------------
// K0b: W -> fp16 transposed WT[n][k]; init encoded f2max.
// ---------------------------------------------------------------------------
__global__ __launch_bounds__(256) void gat_k0b_convert(
    const float* __restrict__ W, _Float16* __restrict__ WT,
    unsigned* __restrict__ f2mxEnc)
{
    const int g = blockIdx.x * 256 + threadIdx.x;      // 65536 threads
    if (g == 0) *f2mxEnc = 0u;                          // enc(-FLT_MAX)
    const int k = g >> 8, n = g & 255;
    WT[n * GAT_F + k] = (_Float16)W[g];
}

// ---------------------------------------------------------------------------
// K1: Wh = h @ W via fp16 MFMA. grid 512 x 256 thr: block = 16 rows,
// wave wv = col-quarter (64 cols, 4 tiles). Cross-wave f1/f2 via LDS.
// ---------------------------------------------------------------------------
__global__ __launch_bounds__(256, 2) void gat_k1_gemm(
    const float* __restrict__ h, const _Float16* __restrict__ WT,
    const float* __restrict__ a, _Float16* __restrict__ whT,
    float* __restrict__ f1L, float* __restrict__ f2L,
    unsigned* __restrict__ f2mxEnc)
{
    __shared__ float sP1[4][16], sP2[4][16];
    const int wv = threadIdx.x >> 6;       // col-quarter
    const int lane = threadIdx.x & 63;
    const int l15 = lane & 15;
    const int quad = lane >> 4;
    const int r0 = blockIdx.x * 16;

    f32x4 acc[4];
    #pragma unroll
    for (int t = 0; t < 4; ++t) { f32x4 z = {0.f,0.f,0.f,0.f}; acc[t] = z; }

    #pragma unroll
    for (int k0 = 0; k0 < GAT_F; k0 += 32) {
        const float* ap = h + (size_t)(r0 + l15) * GAT_F + k0 + quad * 8;
        const float4 a0 = *reinterpret_cast<const float4*>(ap);
        const float4 a1 = *reinterpret_cast<const float4*>(ap + 4);
        half8 af;
        af[0] = (_Float16)a0.x; af[1] = (_Float16)a0.y;
        af[2] = (_Float16)a0.z; af[3] = (_Float16)a0.w;
        af[4] = (_Float16)a1.x; af[5] = (_Float16)a1.y;
        af[6] = (_Float16)a1.z; af[7] = (_Float16)a1.w;
        #pragma unroll
        for (int t = 0; t < 4; ++t) {
            half8 bf = *reinterpret_cast<const half8*>(
                WT + (size_t)(wv * 64 + t * 16 + l15) * GAT_F + k0 + quad * 8);
            acc[t] = __builtin_amdgcn_mfma_f32_16x16x32_f16(af, bf, acc[t], 0, 0, 0);
        }
    }

    // Partial f1/f2 over this wave's 64 cols.
    float p1[4] = {0.f,0.f,0.f,0.f}, p2[4] = {0.f,0.f,0.f,0.f};
    #pragma unroll
    for (int t = 0; t < 4; ++t) {
        float a1c = a[wv * 64 + t * 16 + l15];
        float a2c = a[GAT_F + wv * 64 + t * 16 + l15];
        #pragma unroll
        for (int r = 0; r < 4; ++r) {
            p1[r] = fmaf(acc[t][r], a1c, p1[r]);
            p2[r] = fmaf(acc[t][r], a2c, p2[r]);
        }
    }
    #pragma unroll
    for (int off = 1; off < 16; off <<= 1) {
        #pragma unroll
        for (int r = 0; r < 4; ++r) {
            p1[r] += __shfl_xor(p1[r], off);
            p2[r] += __shfl_xor(p2[r], off);
        }
    }
    if (l15 == 0) {
        #pragma unroll
        for (int r = 0; r < 4; ++r) {
            sP1[wv][quad * 4 + r] = p1[r];
            sP2[wv][quad * 4 + r] = p2[r];
        }
    }
    __syncthreads();
    if (threadIdx.x < 16) {
        const int row = threadIdx.x;
        const float s1 = (sP1[0][row] + sP1[1][row] + sP1[2][row] + sP1[3][row]) * GAT_LOG2E;
        const float s2 = (sP2[0][row] + sP2[1][row] + sP2[2][row] + sP2[3][row]) * GAT_LOG2E;
        f1L[r0 + row] = s1;
        f2L[r0 + row] = s2;
        float mx = s2;
        #pragma unroll
        for (int off = 1; off < 16; off <<= 1) mx = fmaxf(mx, __shfl_xor(mx, off));
        if (row == 0) atomicMax(f2mxEnc, enc_f32(mx));
    }

    // whT[col][row] fp16 store.
    #pragma unroll
    for (int t = 0; t < 4; ++t) {
        half4 hv;
        #pragma unroll
        for (int r = 0; r < 4; ++r) hv[r] = (_Float16)acc[t][r];
        *reinterpret_cast<half4*>(
            whT + (size_t)(wv * 64 + t * 16 + l15) * GAT_N + r0 + quad * 4) = hv;
    }
}

// ---------------------------------------------------------------------------
// K3: fused masked softmax-numerator x V via fp16 MFMA.
// grid = 64 rb x 8 q = 512 blocks, 2 blocks/CU (R4's proven no-spill shape).
// Wave: 32 rows (2 strips) x 256 feats; block iterates its 1024-key slice in
// 16 steps of 64 keys (BK=64 double-buffered LDS, 2 x 32 KB).
// LDS layout is KEY-OCT-MAJOR: chunk(16B) index = koct*256 + feat, so the
// MFMA-side ds_read_b128 bank pattern is c&7 = l15&7 -> 2 lanes/bank-cluster
// per 16-lane phase = conflict-free (fixes R4/R5's 4.2M SQ_LDS_BANK_CONFLICT;
// the old feat-major layout put 8 lanes on one cluster = ~2.9x LDS time).
// Staging: wave wv loads key-octs {wv, wv+4}; global addr is per-lane (free
// mapping), LDS dest = uniform base + lane*16 as global_load_lds requires.
// ---------------------------------------------------------------------------
__global__ __launch_bounds__(256, 2) void gat_k3_attn(
    const unsigned* __restrict__ adjW, const float* __restrict__ f1L,
    const float* __restrict__ f2L, const unsigned* __restrict__ f2mxEnc,
    const _Float16* __restrict__ whT,
    _Float16* __restrict__ Ph,     // 8 slabs x 8192x256 fp16, permuted
    float* __restrict__ L)         // [8][8192]
{
    __shared__ __align__(16) _Float16 sB[2][16384];   // 2 x 32 KB (64-key tile)

    const int bx = blockIdx.x;
    const int rb = bx >> 3;          // row group 0..63
    const int q  = bx & 7;           // key slice 0..7 (bx%8 ~ XCD spread)
    const int wv = threadIdx.x >> 6;
    const int lane = threadIdx.x & 63;
    const int l15 = lane & 15;
    const int quad = lane >> 4;

    const int r0 = rb * 128 + wv * 32;
    const int rA = r0 + l15;
    const int rB = rA + 16;

    const float fmxL = dec_f32(*f2mxEnc);
    const float f1A = f1L[rA];
    const float f1B = f1L[rB];
    const float sA = f1A + fmxL;
    const float sBv = f1B + fmxL;
    const float CA = fmaxf(sA, GAT_ALPHA * sA);
    const float CB = fmaxf(sBv, GAT_ALPHA * sBv);

    f32x4 acc[2][16];
    #pragma unroll
    for (int s = 0; s < 2; ++s)
        #pragma unroll
        for (int t = 0; t < 16; ++t) {
            f32x4 z = {0.f,0.f,0.f,0.f};
            acc[s][t] = z;
        }
    float d0 = 0.f, d1 = 0.f;

    const int kq = q * 1024;
    const uint4* awA = reinterpret_cast<const uint4*>(adjW + (size_t)rA * GAT_NW + q * 32);
    const uint4* awB = reinterpret_cast<const uint4*>(adjW + (size_t)rB * GAT_NW + q * 32);
    const float* f2q = f2L + kq + quad * 8;

    // Staging base: lane = feat-within-64, koct base = wv.
    const _Float16* gst = whT + (size_t)lane * GAT_N + kq + wv * 8;

    // STAGE(buf, step): stage 256 feats x 64 keys (32 KB). Instr i (0..7):
    // koct = wv + (i>>2)*4, feats (i&3)*64 + lane. chunk = koct*256 + feat.
    #define STAGE(buf, step)                                                   \
        {                                                                      \
            _Pragma("unroll")                                                  \
            for (int i = 0; i < 8; ++i) {                                      \
                const _Float16* gp = gst + (size_t)((i & 3) * 64) * GAT_N      \
                                     + (i >> 2) * 32 + (step) * 64;            \
                _Float16* lp = &sB[buf][(((wv + (i >> 2) * 4) * 256            \
                                          + (i & 3) * 64)) * 8];               \
                __builtin_amdgcn_global_load_lds(                              \
                    (const __attribute__((address_space(1))) void*)gp,         \
                    (__attribute__((address_space(3))) void*)lp, 16, 0, 0);    \
            }                                                                  \
        }

    uint4 nA = awA[0];
    uint4 nB = awB[0];
    float4 nfa = *reinterpret_cast<const float4*>(f2q);
    float4 nfb = *reinterpret_cast<const float4*>(f2q + 4);
    STAGE(0, 0)
    __syncthreads();   // buf0 staged (barrier drains vmcnt)

    for (int grp = 0; grp < 8; ++grp) {     // uint4 adj group = 128 keys
        const uint4 cA = nA, cB = nB;
        if (grp < 7) { nA = awA[grp + 1]; nB = awB[grp + 1]; }

        #pragma unroll
        for (int s = 0; s < 2; ++s) {       // step = 64 keys
            const int step = grp * 2 + s;
            const int cur = step & 1;
            if (step + 1 < 16) STAGE(1 - cur, step + 1)

            #pragma unroll
            for (int k2 = 0; k2 < 2; ++k2) {    // sub = 32 keys (one MFMA K)
                const int u = step * 2 + k2;
                const float4 cfa = nfa, cfb = nfb;
                if (u < 31) {
                    nfa = *reinterpret_cast<const float4*>(f2q + (u + 1) * 32);
                    nfb = *reinterpret_cast<const float4*>(f2q + (u + 1) * 32 + 4);
                }
                const int wi = s * 2 + k2;
                const unsigned wA = (wi == 0) ? cA.x : (wi == 1) ? cA.y
                                  : (wi == 2) ? cA.z : cA.w;
                const unsigned wB = (wi == 0) ? cB.x : (wi == 1) ? cB.y
                                  : (wi == 2) ? cB.z : cB.w;
                const unsigned mA = (wA >> (quad * 8)) & 0xffu;
                const unsigned mB = (wB >> (quad * 8)) & 0xffu;
                const float f2v[8] = {cfa.x, cfa.y, cfa.z, cfa.w,
                                      cfb.x, cfb.y, cfb.z, cfb.w};

                half8 pA, pB;
                #pragma unroll
                for (int j = 0; j < 8; ++j) {
                    const float f2j = f2v[j];
                    float xa = f1A + f2j;
                    float la = fmaxf(xa, GAT_ALPHA * xa);
                    float pa = __builtin_amdgcn_exp2f(la - CA);
                    pa = (mA & (1u << j)) ? pa : 0.f;
                    d0 += pa;
                    pA[j] = (_Float16)pa;
                    float xb = f1B + f2j;
                    float lb = fmaxf(xb, GAT_ALPHA * xb);
                    float pb = __builtin_amdgcn_exp2f(lb - CB);
                    pb = (mB & (1u << j)) ? pb : 0.f;
                    d1 += pb;
                    pB[j] = (_Float16)pb;
                }

                // chunk = (k2*4+quad)*256 + t*16 + l15 ; halves index = *8
                const int lbase = (k2 * 1024 + quad * 256 + l15) * 8;
                #pragma unroll
                for (int t = 0; t < 16; ++t) {
                    half8 bf = *reinterpret_cast<const half8*>(
                        &sB[cur][lbase + t * 128]);
                    acc[0][t] = __builtin_amdgcn_mfma_f32_16x16x32_f16(pA, bf, acc[0][t], 0, 0, 0);
                    acc[1][t] = __builtin_amdgcn_mfma_f32_16x16x32_f16(pB, bf, acc[1][t], 0, 0, 0);
                }
            }
            __syncthreads();   // drains stage(step+1) + this step's ds_reads
        }
    }
    #undef STAGE

    // Row denominators: reduce over quads (all lanes end with full row sum).
    d0 += __shfl_xor(d0, 16); d0 += __shfl_xor(d0, 32);
    d1 += __shfl_xor(d1, 16); d1 += __shfl_xor(d1, 32);
    float* Lq = L + q * GAT_N;
    if (lane < 16) { Lq[rA] = d0; Lq[rB] = d1; }

    // Coalesced permuted fp16 partial store: wave-chunk of 8192 halves.
    const int wid = rb * 4 + wv;                       // 0..255
    _Float16* Pq = Ph + ((size_t)q * 256 + wid) * 8192;
    #pragma unroll
    for (int s = 0; s < 2; ++s)
        #pragma unroll
        for (int t = 0; t < 16; ++t) {
            half4 hv;
            #pragma unroll
            for (int r = 0; r < 4; ++r) hv[r] = (_Float16)acc[s][t][r];
            *reinterpret_cast<half4*>(Pq + (size_t)(((s * 16 + t) * 64 + lane) * 4)) = hv;
        }
}

// ---------------------------------------------------------------------------
// K4: un-permute + combine 8 fp16 partials, normalize, ELU, write out.
// ---------------------------------------------------------------------------
__global__ __launch_bounds__(256) void gat_k4_final(
    const _Float16* __restrict__ Ph, const float* __restrict__ L,
    float* __restrict__ out)
{
    const int tid = threadIdx.x;
    const int wid = blockIdx.x >> 3;                   // wave-chunk 0..255
    __shared__ float s_rl[32];
    if (tid < 32) {
        const int row = wid * 32 + tid;
        float s = 0.f;
        #pragma unroll
        for (int q = 0; q < 8; ++q) s += L[q * GAT_N + row];
        s_rl[tid] = 1.0f / fmaxf(s, 1e-30f);
    }
    __syncthreads();

    const int idx = blockIdx.x * 256 + tid;            // half4 position
    const int rem = idx & 2047;                        // within wave-chunk
    const int lane = rem & 63;
    const int st = rem >> 6;
    const int s = st >> 4, t = st & 15;
    const int l15 = lane & 15, quad = lane >> 4;
    const int lrow0 = s * 16 + quad * 4;               // local rows lrow0..+3
    const int col = t * 16 + l15;

    float accv[4] = {0.f, 0.f, 0.f, 0.f};
    #pragma unroll
    for (int q = 0; q < 8; ++q) {
        half4 v = *reinterpret_cast<const half4*>(
            Ph + ((size_t)q * 256 + wid) * 8192 + (size_t)rem * 4);
        #pragma unroll
        for (int r = 0; r < 4; ++r) accv[r] += (float)v[r];
    }
    #pragma unroll
    for (int r = 0; r < 4; ++r) {
        const float v = accv[r] * s_rl[lrow0 + r];
        const float o = v > 0.f ? v : expm1f(v);
        out[(size_t)(wid * 32 + lrow0 + r) * GAT_F + col] = o;
    }
}

// ---------------------------------------------------------------------------
extern "C" void kernel_launch(void* const* d_in, const int* in_sizes, int n_in,
                              void* d_out, int out_size, void* d_ws, size_t ws_size,
                              hipStream_t stream)
{
    const float* h   = (const float*)d_in[0];
    const int*   adj = (const int*)d_in[1];
    // d_in[2] = cv_values: constant per softmax row -> cancels exactly; unused.
    const float* W   = (const float*)d_in[3];
    const float* a   = (const float*)d_in[4];
    float* out = (float*)d_out;
    char* ws = (char*)d_ws;

    const size_t SLAB = (size_t)GAT_N * GAT_F * 2;     // 4 MiB (fp16 matrix)

    size_t off = 0;
    _Float16* whT = (_Float16*)(ws + off); off += SLAB;            // 4 MiB
    _Float16* Ph  = (_Float16*)(ws + off); off += 8 * SLAB;        // 32 MiB
    unsigned char* adjB = (unsigned char*)(ws + off); off += (size_t)GAT_N * GAT_N / 8; // 8 MiB
    _Float16* WT  = (_Float16*)(ws + off); off += (size_t)GAT_F * GAT_F * 2;            // 128 KiB
    float* f1L = (float*)(ws + off); off += GAT_N * 4;
    float* f2L = (float*)(ws + off); off += GAT_N * 4;
    float* L   = (float*)(ws + off); off += 8 * GAT_N * 4;
    unsigned* f2mxEnc = (unsigned*)(ws + off); off += 256;

    gat_k0_pack<<<2048, 256, 0, stream>>>(adj, adjB);
    gat_k0b_convert<<<256, 256, 0, stream>>>(W, WT, f2mxEnc);
    gat_k1_gemm<<<512, 256, 0, stream>>>(h, WT, a, whT, f1L, f2L, f2mxEnc);
    gat_k3_attn<<<512, 256, 0, stream>>>((const unsigned*)adjB, f1L, f2L, f2mxEnc, whT, Ph, L);
    gat_k4_final<<<2048, 256, 0, stream>>>(Ph, L, out);
}

// Round 7
// 466.451 us; speedup vs baseline: 1.2816x; 1.0365x over previous
//
#include <hip/hip_runtime.h>
#include <cstdint>
#include <cstddef>

typedef _Float16 half8 __attribute__((ext_vector_type(8)));
typedef _Float16 half4 __attribute__((ext_vector_type(4)));
typedef float f32x4 __attribute__((ext_vector_type(4)));

#define GAT_N 8192
#define GAT_F 256
#define GAT_NW 256   // adj bitmask words per row (8192/32)
#define GAT_ALPHA 0.2f
#define GAT_LOG2E 1.4426950408889634f

// Monotone float->uint encoding for atomicMax over floats of any sign.
__device__ inline unsigned enc_f32(float x) {
    unsigned b = __float_as_uint(x);
    return (b & 0x80000000u) ? ~b : (b | 0x80000000u);
}
__device__ inline float dec_f32(unsigned u) {
    unsigned b = (u & 0x80000000u) ? (u ^ 0x80000000u) : ~u;
    return __uint_as_float(b);
}

// ---------------------------------------------------------------------------
// K0a: bit-pack adj (int32 0/1, 268 MB) -> adjB (1 bit/edge, 8 MB).
// One wave per row; byte b of a row covers keys [8b, 8b+8), bit j = key 8b+j.
// ---------------------------------------------------------------------------
__global__ __launch_bounds__(256) void gat_k0_pack(
    const int* __restrict__ adj, unsigned char* __restrict__ adjB)
{
    const int wv = threadIdx.x >> 6;
    const int lane = threadIdx.x & 63;
    const int row = blockIdx.x * 4 + wv;
    const int* src = adj + (size_t)row * GAT_N;
    unsigned char* dst = adjB + (size_t)row * (GAT_N / 8);
    #pragma unroll 4
    for (int k = 0; k < 16; ++k) {
        const int4 v0 = *reinterpret_cast<const int4*>(src + k * 512 + lane * 8);
        const int4 v1 = *reinterpret_cast<const int4*>(src + k * 512 + lane * 8 + 4);
        unsigned m = (unsigned)(v0.x > 0)        | ((unsigned)(v0.y > 0) << 1)
                   | ((unsigned)(v0.z > 0) << 2) | ((unsigned)(v0.w > 0) << 3)
                   | ((unsigned)(v1.x > 0) << 4) | ((unsigned)(v1.y > 0) << 5)
                   | ((unsigned)(v1.z > 0) << 6) | ((unsigned)(v1.w > 0) << 7);
        dst[k * 64 + lane] = (unsigned char)m;
    }
}

// ---------------------------------------------------------------------------
// K0b: W -> fp16 transposed WT[n][k]; init encoded f2max.
// ---------------------------------------------------------------------------
__global__ __launch_bounds__(256) void gat_k0b_convert(
    const float* __restrict__ W, _Float16* __restrict__ WT,
    unsigned* __restrict__ f2mxEnc)
{
    const int g = blockIdx.x * 256 + threadIdx.x;      // 65536 threads
    if (g == 0) *f2mxEnc = 0u;                          // enc(-FLT_MAX)
    const int k = g >> 8, n = g & 255;
    WT[n * GAT_F + k] = (_Float16)W[g];
}

// ---------------------------------------------------------------------------
// K1: Wh = h @ W via fp16 MFMA. grid 512 x 256 thr: block = 16 rows,
// wave wv = col-quarter (64 cols, 4 tiles). Cross-wave f1/f2 via LDS.
// ---------------------------------------------------------------------------
__global__ __launch_bounds__(256, 2) void gat_k1_gemm(
    const float* __restrict__ h, const _Float16* __restrict__ WT,
    const float* __restrict__ a, _Float16* __restrict__ whT,
    float* __restrict__ f1L, float* __restrict__ f2L,
    unsigned* __restrict__ f2mxEnc)
{
    __shared__ float sP1[4][16], sP2[4][16];
    const int wv = threadIdx.x >> 6;       // col-quarter
    const int lane = threadIdx.x & 63;
    const int l15 = lane & 15;
    const int quad = lane >> 4;
    const int r0 = blockIdx.x * 16;

    f32x4 acc[4];
    #pragma unroll
    for (int t = 0; t < 4; ++t) { f32x4 z = {0.f,0.f,0.f,0.f}; acc[t] = z; }

    #pragma unroll
    for (int k0 = 0; k0 < GAT_F; k0 += 32) {
        const float* ap = h + (size_t)(r0 + l15) * GAT_F + k0 + quad * 8;
        const float4 a0 = *reinterpret_cast<const float4*>(ap);
        const float4 a1 = *reinterpret_cast<const float4*>(ap + 4);
        half8 af;
        af[0] = (_Float16)a0.x; af[1] = (_Float16)a0.y;
        af[2] = (_Float16)a0.z; af[3] = (_Float16)a0.w;
        af[4] = (_Float16)a1.x; af[5] = (_Float16)a1.y;
        af[6] = (_Float16)a1.z; af[7] = (_Float16)a1.w;
        #pragma unroll
        for (int t = 0; t < 4; ++t) {
            half8 bf = *reinterpret_cast<const half8*>(
                WT + (size_t)(wv * 64 + t * 16 + l15) * GAT_F + k0 + quad * 8);
            acc[t] = __builtin_amdgcn_mfma_f32_16x16x32_f16(af, bf, acc[t], 0, 0, 0);
        }
    }

    // Partial f1/f2 over this wave's 64 cols.
    float p1[4] = {0.f,0.f,0.f,0.f}, p2[4] = {0.f,0.f,0.f,0.f};
    #pragma unroll
    for (int t = 0; t < 4; ++t) {
        float a1c = a[wv * 64 + t * 16 + l15];
        float a2c = a[GAT_F + wv * 64 + t * 16 + l15];
        #pragma unroll
        for (int r = 0; r < 4; ++r) {
            p1[r] = fmaf(acc[t][r], a1c, p1[r]);
            p2[r] = fmaf(acc[t][r], a2c, p2[r]);
        }
    }
    #pragma unroll
    for (int off = 1; off < 16; off <<= 1) {
        #pragma unroll
        for (int r = 0; r < 4; ++r) {
            p1[r] += __shfl_xor(p1[r], off);
            p2[r] += __shfl_xor(p2[r], off);
        }
    }
    if (l15 == 0) {
        #pragma unroll
        for (int r = 0; r < 4; ++r) {
            sP1[wv][quad * 4 + r] = p1[r];
            sP2[wv][quad * 4 + r] = p2[r];
        }
    }
    __syncthreads();
    if (threadIdx.x < 16) {
        const int row = threadIdx.x;
        const float s1 = (sP1[0][row] + sP1[1][row] + sP1[2][row] + sP1[3][row]) * GAT_LOG2E;
        const float s2 = (sP2[0][row] + sP2[1][row] + sP2[2][row] + sP2[3][row]) * GAT_LOG2E;
        f1L[r0 + row] = s1;
        f2L[r0 + row] = s2;
        float mx = s2;
        #pragma unroll
        for (int off = 1; off < 16; off <<= 1) mx = fmaxf(mx, __shfl_xor(mx, off));
        if (row == 0) atomicMax(f2mxEnc, enc_f32(mx));
    }

    // whT[col][row] fp16 store.
    #pragma unroll
    for (int t = 0; t < 4; ++t) {
        half4 hv;
        #pragma unroll
        for (int r = 0; r < 4; ++r) hv[r] = (_Float16)acc[t][r];
        *reinterpret_cast<half4*>(
            whT + (size_t)(wv * 64 + t * 16 + l15) * GAT_N + r0 + quad * 4) = hv;
    }
}

// ---------------------------------------------------------------------------
// K3: fused masked softmax-numerator x V via fp16 MFMA.
// grid = 64 rb x 8 q x 2 fh = 1024 blocks. Feature-split: block = 128 rows x
// 128 feats x 1024-key slice; wave = 32 rows (2 strips) x 128 feats; acc =
// 2x8x4 = 64 VGPR -> slim working set (~115 regs), bounds (256,3) relaxed so
// the allocator is NOT squeezed below the working set (R5's (256,4) forced
// 64 VGPR -> 580 MB scratch spill). Target: <=128 VGPR -> 4 blocks/CU.
// BK=64 double-buffered LDS (2 x 16 KB), key-oct-major conflict-free layout
// (chunk = koct*128 + feat -> 2 lanes/bank-group per phase = free, m136).
// adj: one uint2 (64 keys) per row per step, prefetched 1 step ahead.
// ---------------------------------------------------------------------------
__global__ __launch_bounds__(256, 3) void gat_k3_attn(
    const unsigned* __restrict__ adjW, const float* __restrict__ f1L,
    const float* __restrict__ f2L, const unsigned* __restrict__ f2mxEnc,
    const _Float16* __restrict__ whT,
    _Float16* __restrict__ Ph,     // 8 slabs x 8192x256 fp16, permuted
    float* __restrict__ L)         // [8][8192]
{
    __shared__ __align__(16) _Float16 sB[2][8192];   // 2 x 16 KB (64-key tile)

    const int bx = blockIdx.x;
    const int q  = bx & 7;           // key slice (bx%8 ~ XCD spread)
    const int fh = (bx >> 3) & 1;    // feature half
    const int rb = bx >> 4;          // row group 0..63
    const int wv = threadIdx.x >> 6;
    const int lane = threadIdx.x & 63;
    const int l15 = lane & 15;
    const int quad = lane >> 4;

    const int r0 = rb * 128 + wv * 32;
    const int rA = r0 + l15;
    const int rB = rA + 16;

    const float fmxL = dec_f32(*f2mxEnc);
    const float f1A = f1L[rA];
    const float f1B = f1L[rB];
    const float sA = f1A + fmxL;
    const float sBv = f1B + fmxL;
    const float CA = fmaxf(sA, GAT_ALPHA * sA);
    const float CB = fmaxf(sBv, GAT_ALPHA * sBv);

    f32x4 acc[2][8];
    #pragma unroll
    for (int s = 0; s < 2; ++s)
        #pragma unroll
        for (int t = 0; t < 8; ++t) {
            f32x4 z = {0.f,0.f,0.f,0.f};
            acc[s][t] = z;
        }
    float d0 = 0.f, d1 = 0.f;

    const int kq = q * 1024;
    const uint2* awA = reinterpret_cast<const uint2*>(adjW + (size_t)rA * GAT_NW + q * 32);
    const uint2* awB = reinterpret_cast<const uint2*>(adjW + (size_t)rB * GAT_NW + q * 32);
    const float* f2q = f2L + kq + quad * 8;

    // Staging base: lane = feat-within-64, koct base = wv.
    const _Float16* gst = whT + (size_t)(fh * 128 + lane) * GAT_N + kq + wv * 8;

    // STAGE(buf, step): 128 feats x 64 keys (16 KB), 4 instr/wave.
    // i: koct = wv + (i>>1)*4, feat = (i&1)*64 + lane; chunk = koct*128+feat.
    #define STAGE(buf, step)                                                   \
        {                                                                      \
            _Pragma("unroll")                                                  \
            for (int i = 0; i < 4; ++i) {                                      \
                const _Float16* gp = gst + (size_t)((i & 1) * 64) * GAT_N      \
                                     + (i >> 1) * 32 + (step) * 64;            \
                _Float16* lp = &sB[buf][((wv + (i >> 1) * 4) * 128             \
                                         + (i & 1) * 64) * 8];                 \
                __builtin_amdgcn_global_load_lds(                              \
                    (const __attribute__((address_space(1))) void*)gp,         \
                    (__attribute__((address_space(3))) void*)lp, 16, 0, 0);    \
            }                                                                  \
        }

    uint2 nA = awA[0];
    uint2 nB = awB[0];
    float4 nfa = *reinterpret_cast<const float4*>(f2q);
    float4 nfb = *reinterpret_cast<const float4*>(f2q + 4);
    STAGE(0, 0)
    __syncthreads();   // buf0 staged (barrier drains vmcnt)

    for (int step = 0; step < 16; ++step) {   // 64 keys per step
        const int cur = step & 1;
        const uint2 cA = nA, cB = nB;
        if (step < 15) {
            nA = awA[step + 1];
            nB = awB[step + 1];
            STAGE(1 - cur, step + 1)
        }

        #pragma unroll
        for (int k2 = 0; k2 < 2; ++k2) {    // sub = 32 keys (one MFMA K)
            const int u = step * 2 + k2;
            const float4 cfa = nfa, cfb = nfb;
            if (u < 31) {
                nfa = *reinterpret_cast<const float4*>(f2q + (u + 1) * 32);
                nfb = *reinterpret_cast<const float4*>(f2q + (u + 1) * 32 + 4);
            }
            const unsigned wA = k2 ? cA.y : cA.x;
            const unsigned wB = k2 ? cB.y : cB.x;
            const unsigned mA = (wA >> (quad * 8)) & 0xffu;
            const unsigned mB = (wB >> (quad * 8)) & 0xffu;
            const float f2v[8] = {cfa.x, cfa.y, cfa.z, cfa.w,
                                  cfb.x, cfb.y, cfb.z, cfb.w};

            half8 pA, pB;
            #pragma unroll
            for (int j = 0; j < 8; ++j) {
                const float f2j = f2v[j];
                float xa = f1A + f2j;
                float la = fmaxf(xa, GAT_ALPHA * xa);
                float pa = __builtin_amdgcn_exp2f(la - CA);
                pa = (mA & (1u << j)) ? pa : 0.f;
                d0 += pa;
                pA[j] = (_Float16)pa;
                float xb = f1B + f2j;
                float lb = fmaxf(xb, GAT_ALPHA * xb);
                float pb = __builtin_amdgcn_exp2f(lb - CB);
                pb = (mB & (1u << j)) ? pb : 0.f;
                d1 += pb;
                pB[j] = (_Float16)pb;
            }

            // chunk = (k2*4+quad)*128 + t*16 + l15 ; halves = chunk*8
            const int lbase = (k2 * 4 + quad) * 1024 + l15 * 8;
            #pragma unroll
            for (int t = 0; t < 8; ++t) {
                half8 bf = *reinterpret_cast<const half8*>(
                    &sB[cur][lbase + t * 128]);
                acc[0][t] = __builtin_amdgcn_mfma_f32_16x16x32_f16(pA, bf, acc[0][t], 0, 0, 0);
                acc[1][t] = __builtin_amdgcn_mfma_f32_16x16x32_f16(pB, bf, acc[1][t], 0, 0, 0);
            }
        }
        __syncthreads();   // drains stage(step+1) + this step's ds_reads
    }
    #undef STAGE

    // Row denominators (identical in both fh halves; fh==0 writes).
    d0 += __shfl_xor(d0, 16); d0 += __shfl_xor(d0, 32);
    d1 += __shfl_xor(d1, 16); d1 += __shfl_xor(d1, 32);
    if (fh == 0 && lane < 16) {
        float* Lq = L + q * GAT_N;
        Lq[rA] = d0; Lq[rB] = d1;
    }

    // Coalesced permuted fp16 partial store; fh selects tile range.
    const int wid = rb * 4 + wv;                       // 0..255
    _Float16* Pq = Ph + ((size_t)q * 256 + wid) * 8192;
    #pragma unroll
    for (int s = 0; s < 2; ++s)
        #pragma unroll
        for (int t = 0; t < 8; ++t) {
            const int tt = fh * 8 + t;
            half4 hv;
            #pragma unroll
            for (int r = 0; r < 4; ++r) hv[r] = (_Float16)acc[s][t][r];
            *reinterpret_cast<half4*>(Pq + (size_t)(((s * 16 + tt) * 64 + lane) * 4)) = hv;
        }
}

// ---------------------------------------------------------------------------
// K4: un-permute + combine 8 fp16 partials, normalize, ELU, write out.
// ---------------------------------------------------------------------------
__global__ __launch_bounds__(256) void gat_k4_final(
    const _Float16* __restrict__ Ph, const float* __restrict__ L,
    float* __restrict__ out)
{
    const int tid = threadIdx.x;
    const int wid = blockIdx.x >> 3;                   // wave-chunk 0..255
    __shared__ float s_rl[32];
    if (tid < 32) {
        const int row = wid * 32 + tid;
        float s = 0.f;
        #pragma unroll
        for (int q = 0; q < 8; ++q) s += L[q * GAT_N + row];
        s_rl[tid] = 1.0f / fmaxf(s, 1e-30f);
    }
    __syncthreads();

    const int idx = blockIdx.x * 256 + tid;            // half4 position
    const int rem = idx & 2047;                        // within wave-chunk
    const int lane = rem & 63;
    const int st = rem >> 6;
    const int s = st >> 4, t = st & 15;
    const int l15 = lane & 15, quad = lane >> 4;
    const int lrow0 = s * 16 + quad * 4;               // local rows lrow0..+3
    const int col = t * 16 + l15;

    float accv[4] = {0.f, 0.f, 0.f, 0.f};
    #pragma unroll
    for (int q = 0; q < 8; ++q) {
        half4 v = *reinterpret_cast<const half4*>(
            Ph + ((size_t)q * 256 + wid) * 8192 + (size_t)rem * 4);
        #pragma unroll
        for (int r = 0; r < 4; ++r) accv[r] += (float)v[r];
    }
    #pragma unroll
    for (int r = 0; r < 4; ++r) {
        const float v = accv[r] * s_rl[lrow0 + r];
        const float o = v > 0.f ? v : expm1f(v);
        out[(size_t)(wid * 32 + lrow0 + r) * GAT_F + col] = o;
    }
}

// ---------------------------------------------------------------------------
extern "C" void kernel_launch(void* const* d_in, const int* in_sizes, int n_in,
                              void* d_out, int out_size, void* d_ws, size_t ws_size,
                              hipStream_t stream)
{
    const float* h   = (const float*)d_in[0];
    const int*   adj = (const int*)d_in[1];
    // d_in[2] = cv_values: constant per softmax row -> cancels exactly; unused.
    const float* W   = (const float*)d_in[3];
    const float* a   = (const float*)d_in[4];
    float* out = (float*)d_out;
    char* ws = (char*)d_ws;

    const size_t SLAB = (size_t)GAT_N * GAT_F * 2;     // 4 MiB (fp16 matrix)

    size_t off = 0;
    _Float16* whT = (_Float16*)(ws + off); off += SLAB;            // 4 MiB
    _Float16* Ph  = (_Float16*)(ws + off); off += 8 * SLAB;        // 32 MiB
    unsigned char* adjB = (unsigned char*)(ws + off); off += (size_t)GAT_N * GAT_N / 8; // 8 MiB
    _Float16* WT  = (_Float16*)(ws + off); off += (size_t)GAT_F * GAT_F * 2;            // 128 KiB
    float* f1L = (float*)(ws + off); off += GAT_N * 4;
    float* f2L = (float*)(ws + off); off += GAT_N * 4;
    float* L   = (float*)(ws + off); off += 8 * GAT_N * 4;
    unsigned* f2mxEnc = (unsigned*)(ws + off); off += 256;

    gat_k0_pack<<<2048, 256, 0, stream>>>(adj, adjB);
    gat_k0b_convert<<<256, 256, 0, stream>>>(W, WT, f2mxEnc);
    gat_k1_gemm<<<512, 256, 0, stream>>>(h, WT, a, whT, f1L, f2L, f2mxEnc);
    gat_k3_attn<<<1024, 256, 0, stream>>>((const unsigned*)adjB, f1L, f2L, f2mxEnc, whT, Ph, L);
    gat_k4_final<<<2048, 256, 0, stream>>>(Ph, L, out);
}